// Round 8
// baseline (321.847 us; speedup 1.0000x reference)
//
#include <hip/hip_runtime.h>

#define BB 32
#define H 256
#define W 256
#define NC 25
#define TH 8     // tile rows
#define TW 128   // tile cols
#define GH 16    // TH + 2*4 halo
#define GW 136   // TW + 2*4 halo
#define AH 12    // TH + 2*2
#define AW 132   // TW + 2*2

__global__ __launch_bounds__(256)
void gtnet_fused(const float* __restrict__ im_input,
                 const float* __restrict__ m_kernel,
                 const int* __restrict__ gt,
                 float* __restrict__ out_pred,
                 float* __restrict__ out_mask,
                 float* __restrict__ out_app)
{
    __shared__ float s_wk[NC * NC];                 // 2.5 KB  [cls][i*5+j]
    __shared__ __align__(16) int    s_gt[GH][GW];   // 8.7 KB, -1 = OOB
    __shared__ __align__(16) float4 s_img[AH][AW];  // 25.3 KB {im0*a, im1*a, im2*a, a}

    const int tid = threadIdx.x;
    const int bx  = blockIdx.x;
    const int tiles_per_img = (H / TH) * (W / TW);  // 64
    const int b  = bx / tiles_per_img;
    const int t  = bx % tiles_per_img;
    const int oh = (t >> 1) * TH;                   // 0..248 step 8
    const int ow = (t & 1) * TW;                    // 0 or 128

    // ---- stage weights + gt tile (halo 4) ----
    for (int i = tid; i < NC * NC; i += 256) s_wk[i] = m_kernel[i];

    const int* gtb = gt + b * (H * W);
    for (int i = tid; i < GH * GW; i += 256) {
        int y = i / GW, x = i - y * GW;
        int gy = oh - 4 + y, gx = ow - 4 + x;
        int v = -1;
        if (gy >= 0 && gy < H && gx >= 0 && gx < W) v = gtb[gy * W + gx];
        s_gt[y][x] = v;
    }
    __syncthreads();

    // ---- one-hot m_mask: 512B-contiguous chunks per wave, fire early ----
    {
        float* mb = out_mask + (size_t)b * (NC * H * W) + (size_t)oh * W + ow;
        const int r  = tid >> 5;          // 0..7
        const int c4 = (tid & 31) * 4;    // 0..124
        const int4 g = *reinterpret_cast<const int4*>(&s_gt[4 + r][4 + c4]);
        const size_t ro = (size_t)r * W + c4;
        #pragma unroll
        for (int c = 0; c < NC; ++c) {
            float4 v;
            v.x = (g.x == c) ? 1.f : 0.f;
            v.y = (g.y == c) ? 1.f : 0.f;
            v.z = (g.z == c) ? 1.f : 0.f;
            v.w = (g.w == c) ? 1.f : 0.f;
            *reinterpret_cast<float4*>(&mb[(size_t)c * (H * W) + ro]) = v;
        }
    }

    // ---- appear + gated image staging (12x132), out_app stored inline ----
    {
        const float* imb = im_input + ((size_t)b * 6 + 3) * (H * W);
        float* ab = out_app + (size_t)b * (H * W);
        for (int idx = tid; idx < AH * AW; idx += 256) {
            int p = idx / AW, q = idx - p * AW;
            float seg = 0.f;
            #pragma unroll
            for (int i = 0; i < 5; ++i)
                #pragma unroll
                for (int j = 0; j < 5; ++j) {
                    int cls = s_gt[p + i][q + j];
                    seg += (cls >= 0) ? s_wk[cls * NC + i * 5 + j] : 0.f;
                }
            float app = fmaxf(1.f - fmaxf(seg - 1.f, 0.f), 0.f);
            int gy = oh - 2 + p, gx = ow - 2 + q;
            float4 v; v.x = 0.f; v.y = 0.f; v.z = 0.f; v.w = app;
            if (gy >= 0 && gy < H && gx >= 0 && gx < W) {
                int o = gy * W + gx;
                v.x = imb[o] * app;
                v.y = imb[H * W + o] * app;
                v.z = imb[2 * H * W + o] * app;
            }
            s_img[p][q] = v;
            if (p >= 2 && p < 2 + TH && q >= 2 && q < 2 + TW)
                ab[(size_t)(oh + p - 2) * W + (ow + q - 2)] = 1.f - app;
        }
    }
    __syncthreads();

    // ---- pred: each thread owns a 4-row x 1-col patch (lanes stride-1 in x) ----
    {
        const int x0 = tid & 127;          // col in tile
        const int y0 = (tid >> 7) * 4;     // 0 or 4
        float acc[4][3];
        #pragma unroll
        for (int dy = 0; dy < 4; ++dy) {
            acc[dy][0] = 0.f; acc[dy][1] = 0.f; acc[dy][2] = 0.f;
        }

        #pragma unroll
        for (int sy = 0; sy < 8; ++sy) {
            #pragma unroll
            for (int sx = 0; sx < 5; ++sx) {
                const int p = y0 + sy, q = x0 + sx;
                const float4 im4 = s_img[p][q];
                const int cls = s_gt[p + 2][q + 2];
                const int cw  = (cls >= 0) ? cls * NC : 0;  // im4 zero at OOB
                #pragma unroll
                for (int dy = 0; dy < 4; ++dy) {
                    const int i = sy - dy;
                    if (i < 0 || i > 4) continue;
                    const float w = s_wk[cw + i * 5 + sx];
                    acc[dy][0] += im4.x * w;
                    acc[dy][1] += im4.y * w;
                    acc[dy][2] += im4.z * w;
                }
            }
        }

        float* pb = out_pred + (size_t)b * 3 * H * W;
        #pragma unroll
        for (int ch = 0; ch < 3; ++ch)
            #pragma unroll
            for (int dy = 0; dy < 4; ++dy)
                pb[(size_t)(ch * H + oh + y0 + dy) * W + ow + x0] = acc[dy][ch];
    }
}

extern "C" void kernel_launch(void* const* d_in, const int* in_sizes, int n_in,
                              void* d_out, int out_size, void* d_ws, size_t ws_size,
                              hipStream_t stream) {
    const float* im_input = (const float*)d_in[0];   // [32, 6, 256, 256] f32
    const float* m_kernel = (const float*)d_in[1];   // [1, 25, 5, 5]    f32
    const int*   gt       = (const int*)d_in[2];     // [32, 1, 256, 256] i32

    float* out_pred = (float*)d_out;                              // [32,3,256,256]
    float* out_mask = out_pred + (size_t)BB * 3 * H * W;          // [32,25,256,256]
    float* out_app  = out_mask + (size_t)BB * NC * H * W;         // [32,1,256,256]

    const int blocks = BB * (H / TH) * (W / TW);  // 2048
    gtnet_fused<<<blocks, 256, 0, stream>>>(im_input, m_kernel, gt,
                                            out_pred, out_mask, out_app);
}

// Round 10
// 319.224 us; speedup vs baseline: 1.0082x; 1.0082x over previous
//
#include <hip/hip_runtime.h>

#define BB 32
#define H 256
#define W 256
#define NC 25
#define TH 8     // tile rows
#define TW 128   // tile cols
#define GH 16    // TH + 2*4 halo
#define GW 136   // TW + 2*4 halo
#define AH 12    // TH + 2*2
#define AW 132   // TW + 2*2

typedef float f4 __attribute__((ext_vector_type(4)));

__global__ __launch_bounds__(256)
void gtnet_fused(const float* __restrict__ im_input,
                 const float* __restrict__ m_kernel,
                 const int* __restrict__ gt,
                 float* __restrict__ out_pred,
                 float* __restrict__ out_mask,
                 float* __restrict__ out_app)
{
    __shared__ float s_wk[NC * NC];                 // 2.5 KB  [cls][i*5+j]
    __shared__ __align__(16) int    s_gt[GH][GW];   // 8.7 KB, -1 = OOB
    __shared__ __align__(16) float4 s_img[AH][AW];  // 25.3 KB {im0*a, im1*a, im2*a, a}

    const int tid = threadIdx.x;
    const int bx  = blockIdx.x;
    const int tiles_per_img = (H / TH) * (W / TW);  // 64
    const int b  = bx / tiles_per_img;
    const int t  = bx % tiles_per_img;
    const int oh = (t >> 1) * TH;                   // 0..248 step 8
    const int ow = (t & 1) * TW;                    // 0 or 128

    // ---- stage weights + gt tile (halo 4) ----
    for (int i = tid; i < NC * NC; i += 256) s_wk[i] = m_kernel[i];

    const int* gtb = gt + b * (H * W);
    for (int i = tid; i < GH * GW; i += 256) {
        int y = i / GW, x = i - y * GW;
        int gy = oh - 4 + y, gx = ow - 4 + x;
        int v = -1;
        if (gy >= 0 && gy < H && gx >= 0 && gx < W) v = gtb[gy * W + gx];
        s_gt[y][x] = v;
    }
    __syncthreads();

    // ---- one-hot m_mask: 512B-contiguous chunks per wave, nontemporal (never re-read) ----
    {
        float* mb = out_mask + (size_t)b * (NC * H * W) + (size_t)oh * W + ow;
        const int r  = tid >> 5;          // 0..7
        const int c4 = (tid & 31) * 4;    // 0..124
        const int4 g = *reinterpret_cast<const int4*>(&s_gt[4 + r][4 + c4]);
        const size_t ro = (size_t)r * W + c4;
        #pragma unroll
        for (int c = 0; c < NC; ++c) {
            f4 v;
            v.x = (g.x == c) ? 1.f : 0.f;
            v.y = (g.y == c) ? 1.f : 0.f;
            v.z = (g.z == c) ? 1.f : 0.f;
            v.w = (g.w == c) ? 1.f : 0.f;
            __builtin_nontemporal_store(v, reinterpret_cast<f4*>(&mb[(size_t)c * (H * W) + ro]));
        }
    }

    // ---- appear + gated image staging (12x132), out_app stored inline (nt) ----
    {
        const float* imb = im_input + ((size_t)b * 6 + 3) * (H * W);
        float* ab = out_app + (size_t)b * (H * W);
        for (int idx = tid; idx < AH * AW; idx += 256) {
            int p = idx / AW, q = idx - p * AW;
            float seg = 0.f;
            #pragma unroll
            for (int i = 0; i < 5; ++i)
                #pragma unroll
                for (int j = 0; j < 5; ++j) {
                    int cls = s_gt[p + i][q + j];
                    seg += (cls >= 0) ? s_wk[cls * NC + i * 5 + j] : 0.f;
                }
            float app = fmaxf(1.f - fmaxf(seg - 1.f, 0.f), 0.f);
            int gy = oh - 2 + p, gx = ow - 2 + q;
            float4 v; v.x = 0.f; v.y = 0.f; v.z = 0.f; v.w = app;
            if (gy >= 0 && gy < H && gx >= 0 && gx < W) {
                int o = gy * W + gx;
                v.x = imb[o] * app;
                v.y = imb[H * W + o] * app;
                v.z = imb[2 * H * W + o] * app;
            }
            s_img[p][q] = v;
            if (p >= 2 && p < 2 + TH && q >= 2 && q < 2 + TW)
                __builtin_nontemporal_store(1.f - app,
                    &ab[(size_t)(oh + p - 2) * W + (ow + q - 2)]);
        }
    }
    __syncthreads();

    // ---- pred: each thread owns a 4-row x 1-col patch (lanes stride-1 in x) ----
    {
        const int x0 = tid & 127;          // col in tile
        const int y0 = (tid >> 7) * 4;     // 0 or 4
        float acc[4][3];
        #pragma unroll
        for (int dy = 0; dy < 4; ++dy) {
            acc[dy][0] = 0.f; acc[dy][1] = 0.f; acc[dy][2] = 0.f;
        }

        #pragma unroll
        for (int sy = 0; sy < 8; ++sy) {
            #pragma unroll
            for (int sx = 0; sx < 5; ++sx) {
                const int p = y0 + sy, q = x0 + sx;
                const float4 im4 = s_img[p][q];
                const int cls = s_gt[p + 2][q + 2];
                const int cw  = (cls >= 0) ? cls * NC : 0;  // im4 zero at OOB
                #pragma unroll
                for (int dy = 0; dy < 4; ++dy) {
                    const int i = sy - dy;
                    if (i < 0 || i > 4) continue;
                    const float w = s_wk[cw + i * 5 + sx];
                    acc[dy][0] += im4.x * w;
                    acc[dy][1] += im4.y * w;
                    acc[dy][2] += im4.z * w;
                }
            }
        }

        float* pb = out_pred + (size_t)b * 3 * H * W;
        #pragma unroll
        for (int ch = 0; ch < 3; ++ch)
            #pragma unroll
            for (int dy = 0; dy < 4; ++dy)
                __builtin_nontemporal_store(acc[dy][ch],
                    &pb[(size_t)(ch * H + oh + y0 + dy) * W + ow + x0]);
    }
}

extern "C" void kernel_launch(void* const* d_in, const int* in_sizes, int n_in,
                              void* d_out, int out_size, void* d_ws, size_t ws_size,
                              hipStream_t stream) {
    const float* im_input = (const float*)d_in[0];   // [32, 6, 256, 256] f32
    const float* m_kernel = (const float*)d_in[1];   // [1, 25, 5, 5]    f32
    const int*   gt       = (const int*)d_in[2];     // [32, 1, 256, 256] i32

    float* out_pred = (float*)d_out;                              // [32,3,256,256]
    float* out_mask = out_pred + (size_t)BB * 3 * H * W;          // [32,25,256,256]
    float* out_app  = out_mask + (size_t)BB * NC * H * W;         // [32,1,256,256]

    const int blocks = BB * (H / TH) * (W / TW);  // 2048
    gtnet_fused<<<blocks, 256, 0, stream>>>(im_input, m_kernel, gt,
                                            out_pred, out_mask, out_app);
}